// Round 9
// baseline (206.094 us; speedup 1.0000x reference)
//
#include <hip/hip_runtime.h>
#include <math.h>

#define DM 1024
#define DI 2048
#define NS 16
#define DTR 64
#define LL 2048
#define NXDBL 96      // DTR + 2*NS
#define NCHUNK 64
#define CHLEN 32      // LL / NCHUNK

typedef unsigned short u16;
typedef __attribute__((ext_vector_type(8))) short short8;
typedef __attribute__((ext_vector_type(4))) float f32x4;

__device__ __forceinline__ float sigmoidf_(float x) { return 1.f / (1.f + __expf(-x)); }
__device__ __forceinline__ float siluf_(float x) { return x * sigmoidf_(x); }
__device__ __forceinline__ float softplus_fast(float x) {
    return fmaxf(x, 0.f) + __logf(1.f + __expf(-fabsf(x)));
}
__device__ __forceinline__ u16 f2b(float f) {  // fp32 -> bf16 RNE
    unsigned u = __float_as_uint(f);
    return (u16)((u + 0x7FFFu + ((u >> 16) & 1u)) >> 16);
}
__device__ __forceinline__ float b2f(u16 h) {
    return __uint_as_float(((unsigned)h) << 16);
}

// ---------------- fp32 -> bf16 plain convert (4 elems/thread) -----------------
__global__ __launch_bounds__(256) void convert_plain(const float* __restrict__ src,
                                                     u16* __restrict__ dst) {
    const int i = (blockIdx.x * 256 + threadIdx.x) * 4;
    float4 v = *(const float4*)&src[i];
    u16 o[4] = {f2b(v.x), f2b(v.y), f2b(v.z), f2b(v.w)};
    *(ushort4*)&dst[i] = *(ushort4*)o;
}

// ---------------- fp32 [R][C] -> bf16 [C][R] transpose convert -----------------
__global__ __launch_bounds__(256) void convert_T(const float* __restrict__ src,
                                                 u16* __restrict__ dst, int R, int C) {
    __shared__ float t[32][33];
    const int tx = threadIdx.x & 31, ty = threadIdx.x >> 5;  // ty 0..7
    const int c0 = blockIdx.x * 32, r0 = blockIdx.y * 32;
#pragma unroll
    for (int i = 0; i < 4; i++)
        t[ty + i * 8][tx] = src[(size_t)(r0 + ty + i * 8) * C + c0 + tx];
    __syncthreads();
#pragma unroll
    for (int i = 0; i < 4; i++)
        dst[(size_t)(c0 + ty + i * 8) * R + r0 + tx] = f2b(t[tx][ty + i * 8]);
}

__global__ __launch_bounds__(256) void fill_zero_u16(u16* __restrict__ p, int n) {
    const int i = blockIdx.x * 256 + threadIdx.x;
    if (i < n) p[i] = 0;
}

// ---------------- bf16 MFMA GEMM: C[M][N] = A[M][K] @ Bt[N][K]^T -----------------
// 128x128 tile, BK=32, K = NSTEPS*32. 3-buffer LDS pipeline, prefetch distance 2,
// counted s_waitcnt vmcnt(N) + raw s_barrier. LDS k-group XOR swizzle
// (kg' = kg ^ ((row>>1)&3)) on the per-lane GLOBAL source (write) and the
// ds_read offset (read); LDS stays linear for global_load_lds.
// EPI==1: cols [0,DI) -> bf16 C0h; cols [DI,2DI) -> bf16 C1h = silu(v) (gate).
// EPI==0: fp32 partial to C0 + blockIdx.z*M*N (split-K over gridDim.z).
#define WAITV(N) asm volatile("s_waitcnt vmcnt(" #N ")" ::: "memory")
template <int EPI, int NSTEPS>
__global__ __launch_bounds__(256) void gemm_mfma(const u16* __restrict__ A,
                                                 const u16* __restrict__ Bt,
                                                 void* __restrict__ C0,
                                                 void* __restrict__ C1,
                                                 int M, int N, int lda) {
    __shared__ u16 As[3][128 * 32];
    __shared__ u16 Bs[3][128 * 32];
    const int tid = threadIdx.x;
    const int lane = tid & 63;
    const int wave = tid >> 6;
    const int bm = blockIdx.y * 128, bn = blockIdx.x * 128;
    const int wr = wave >> 1, wc = wave & 1;
    const int k_off = blockIdx.z * (NSTEPS * 32);

    f32x4 acc[4][4];
#pragma unroll
    for (int m = 0; m < 4; m++)
#pragma unroll
        for (int n = 0; n < 4; n++) acc[m][n] = (f32x4)0.f;

    // staging: thread tid -> (row = tid>>2, kg = tid&3), LDS linear at tid*16B.
    const int srow = tid >> 2;
    const int swz = (tid >> 3) & 3;                    // (srow>>1)&3
    const int skel = (((tid & 3) ^ swz) << 3);         // swizzled k elem offset
    const u16* Ag0 = A + (size_t)(bm + srow) * lda + k_off + skel;
    const u16* Ag1 = A + (size_t)(bm + 64 + srow) * lda + k_off + skel;
    const u16* Bg0 = Bt + (size_t)(bn + srow) * lda + k_off + skel;
    const u16* Bg1 = Bt + (size_t)(bn + 64 + srow) * lda + k_off + skel;
    u16* Asl = &As[0][0] + tid * 8;
    u16* Bsl = &Bs[0][0] + tid * 8;

    // fragment read offsets (u16 units), same swizzle on the kg index
    const int rsw = (lane >> 1) & 3;                   // row bits 1-2
    const int arow = (wr * 64 + (lane & 15)) * 32 + (((lane >> 4) ^ rsw) << 3);
    const int brow = (wc * 64 + (lane & 15)) * 32 + (((lane >> 4) ^ rsw) << 3);

#define STAGE(buf, ks)                                                               \
    do {                                                                             \
        __builtin_amdgcn_global_load_lds(                                            \
            (const __attribute__((address_space(1))) unsigned*)(Ag0 + (ks)),         \
            (__attribute__((address_space(3))) unsigned*)(Asl + (buf) * 4096),       \
            16, 0, 0);                                                               \
        __builtin_amdgcn_global_load_lds(                                            \
            (const __attribute__((address_space(1))) unsigned*)(Ag1 + (ks)),         \
            (__attribute__((address_space(3))) unsigned*)(Asl + (buf) * 4096 + 2048),\
            16, 0, 0);                                                               \
        __builtin_amdgcn_global_load_lds(                                            \
            (const __attribute__((address_space(1))) unsigned*)(Bg0 + (ks)),         \
            (__attribute__((address_space(3))) unsigned*)(Bsl + (buf) * 4096),       \
            16, 0, 0);                                                               \
        __builtin_amdgcn_global_load_lds(                                            \
            (const __attribute__((address_space(1))) unsigned*)(Bg1 + (ks)),         \
            (__attribute__((address_space(3))) unsigned*)(Bsl + (buf) * 4096 + 2048),\
            16, 0, 0);                                                               \
    } while (0)

#define COMPUTE(buf)                                                                 \
    do {                                                                             \
        short8 av[4], bv[4];                                                         \
        _Pragma("unroll") for (int m = 0; m < 4; m++)                                \
            av[m] = *(const short8*)&As[buf][arow + m * 512];                        \
        _Pragma("unroll") for (int n = 0; n < 4; n++)                                \
            bv[n] = *(const short8*)&Bs[buf][brow + n * 512];                        \
        _Pragma("unroll") for (int m = 0; m < 4; m++)                                \
            _Pragma("unroll") for (int n = 0; n < 4; n++)                            \
                acc[m][n] = __builtin_amdgcn_mfma_f32_16x16x32_bf16(av[m], bv[n],    \
                                                                    acc[m][n], 0, 0, 0); \
    } while (0)

    STAGE(0, 0);
    if (NSTEPS > 1) STAGE(1, 32);
#pragma unroll
    for (int s = 0; s < NSTEPS; ++s) {
        if (s + 2 < NSTEPS) {
            STAGE((s + 2) % 3, (s + 2) * 32);
            WAITV(8);                      // oldest 4 (tile s) complete; 8 in flight
        } else if (s + 1 < NSTEPS) {
            WAITV(4);
        } else {
            WAITV(0);
        }
        __builtin_amdgcn_s_barrier();      // tile s visible to all waves
        COMPUTE(s % 3);
        __builtin_amdgcn_s_barrier();      // reads done before buf reuse
    }
#undef STAGE
#undef COMPUTE

    const int crow0 = bm + wr * 64 + (lane >> 4) * 4;
    const int ccol0 = bn + wc * 64 + (lane & 15);
#pragma unroll
    for (int m = 0; m < 4; m++)
#pragma unroll
        for (int n = 0; n < 4; n++) {
            const int col = ccol0 + n * 16;
#pragma unroll
            for (int r = 0; r < 4; r++) {
                const int row = crow0 + m * 16 + r;
                const float v = acc[m][n][r];
                if (EPI == 1) {
                    u16* C0h = (u16*)C0;       // xc (bf16)
                    u16* C1h = (u16*)C1;       // gate = silu(res) (bf16)
                    if (col < DI)
                        C0h[(size_t)row * DI + col] = f2b(v);
                    else
                        C1h[(size_t)row * DI + col - DI] = f2b(siluf_(v));
                } else {
                    float* C0z = (float*)C0 + (size_t)blockIdx.z * M * N;
                    C0z[(size_t)row * N + col] = v;
                }
            }
        }
}

// ---------------- fp32 GEMM 128x128 tile, 8x8 micro, BK=16: dt path (K=64) -------
// dt = softplus(xdbl[:, :64] @ W_dt + b_dt), written as bf16.
__global__ __launch_bounds__(256) void gemm128_dt(const float* __restrict__ A,
                                                  const float* __restrict__ B,
                                                  const float* __restrict__ bias,
                                                  u16* __restrict__ C,
                                                  int N, int K, int lda) {
    __shared__ float As[16][128];
    __shared__ float Bs[16][128];
    const int tid = threadIdx.x;
    const int bm = blockIdx.y * 128, bn = blockIdx.x * 128;
    const int ty = tid >> 4, tx = tid & 15;
    float acc[8][8];
#pragma unroll
    for (int i = 0; i < 8; i++)
#pragma unroll
        for (int j = 0; j < 8; j++) acc[i][j] = 0.f;

    const int ar = tid >> 2, ak = (tid & 3) << 2;
    const int bk = tid >> 5, bc = (tid & 31) << 2;

    for (int k0 = 0; k0 < K; k0 += 16) {
        float4 a0 = *(const float4*)&A[(size_t)(bm + ar) * lda + k0 + ak];
        float4 a1 = *(const float4*)&A[(size_t)(bm + ar + 64) * lda + k0 + ak];
        float4 b0 = *(const float4*)&B[(size_t)(k0 + bk) * N + bn + bc];
        float4 b1 = *(const float4*)&B[(size_t)(k0 + bk + 8) * N + bn + bc];
        __syncthreads();
        As[ak + 0][ar] = a0.x; As[ak + 1][ar] = a0.y;
        As[ak + 2][ar] = a0.z; As[ak + 3][ar] = a0.w;
        As[ak + 0][ar + 64] = a1.x; As[ak + 1][ar + 64] = a1.y;
        As[ak + 2][ar + 64] = a1.z; As[ak + 3][ar + 64] = a1.w;
        *(float4*)&Bs[bk][bc] = b0;
        *(float4*)&Bs[bk + 8][bc] = b1;
        __syncthreads();
#pragma unroll
        for (int k = 0; k < 16; k++) {
            float a[8], b[8];
            *(float4*)&a[0] = *(const float4*)&As[k][ty * 8];
            *(float4*)&a[4] = *(const float4*)&As[k][ty * 8 + 4];
            *(float4*)&b[0] = *(const float4*)&Bs[k][tx * 8];
            *(float4*)&b[4] = *(const float4*)&Bs[k][tx * 8 + 4];
#pragma unroll
            for (int i = 0; i < 8; i++)
#pragma unroll
                for (int j = 0; j < 8; j++) acc[i][j] = fmaf(a[i], b[j], acc[i][j]);
        }
    }
#pragma unroll
    for (int i = 0; i < 8; i++) {
        const int row = bm + ty * 8 + i;
#pragma unroll
        for (int j = 0; j < 8; j += 4) {
            const int col = bn + tx * 8 + j;
            const float4 bi = *(const float4*)&bias[col];
            u16 o[4] = {f2b(softplus_fast(acc[i][j] + bi.x)),
                        f2b(softplus_fast(acc[i][j + 1] + bi.y)),
                        f2b(softplus_fast(acc[i][j + 2] + bi.z)),
                        f2b(softplus_fast(acc[i][j + 3] + bi.w))};
            *(ushort4*)&C[(size_t)row * N + col] = *(ushort4*)o;
        }
    }
}

// ---------------- sum of 2 split-K partials -----------------
__global__ __launch_bounds__(256) void sum2(const float* __restrict__ p,
                                            float* __restrict__ out, int n) {
    const int i = (blockIdx.x * 256 + threadIdx.x) * 4;
    float4 a = *(const float4*)&p[i];
    float4 b = *(const float4*)&p[(size_t)n + i];
    *(float4*)&out[i] = make_float4(a.x + b.x, a.y + b.y, a.z + b.z, a.w + b.w);
}

// ---------------- reduce 16 split-K partials [z][L][128] -> xdbl [L][96] ---------
__global__ __launch_bounds__(256) void g2reduce(const float* __restrict__ part,
                                                float* __restrict__ xdbl) {
    const int gid = blockIdx.x * 256 + threadIdx.x;
    if (gid < LL * NXDBL) {
        const int row = gid / NXDBL;
        const int col = gid - row * NXDBL;
        float s = 0.f;
#pragma unroll
        for (int z = 0; z < 16; z++) s += part[((size_t)z * LL + row) * 128 + col];
        xdbl[gid] = s;
    }
}

// ---------------- conv (k=4, causal) + silu: bf16 in -> bf16 out -----------------
__global__ __launch_bounds__(256) void conv_silu(const u16* __restrict__ xcb,
                                                 const float* __restrict__ cw,
                                                 const float* __restrict__ cb,
                                                 u16* __restrict__ xsb) {
    const int gid = blockIdx.x * 256 + threadIdx.x;  // l*DI + d
    const int l = gid >> 11;
    const int d = gid & (DI - 1);
    const float4 w = *(const float4*)&cw[d * 4];
    float acc = cb[d];
    const float wj[4] = {w.x, w.y, w.z, w.w};
#pragma unroll
    for (int j = 0; j < 4; j++) {
        const int li = l + j - 3;
        if (li >= 0) acc = fmaf(b2f(xcb[(size_t)li * DI + d]), wj[j], acc);
    }
    xsb[gid] = f2b(siluf_(acc));
}

// ---------------- scan phase 1: per-chunk composition, 16 states/thread ---------
__global__ __launch_bounds__(256) void scan_phase1(const u16* __restrict__ dtb,
                                                   const u16* __restrict__ xsb,
                                                   const float* __restrict__ xdbl,
                                                   const float* __restrict__ A_log,
                                                   float* __restrict__ chA,
                                                   float* __restrict__ chB) {
    const int g = blockIdx.x * 256 + threadIdx.x;
    const int d = g & (DI - 1);
    const int c = g >> 11;
    float An2[NS], ap[NS], bc[NS];
    {
        float al[NS];
#pragma unroll
        for (int q = 0; q < 4; q++)
            *(float4*)&al[q * 4] = *(const float4*)&A_log[d * NS + q * 4];
#pragma unroll
        for (int n = 0; n < NS; n++) {
            An2[n] = -__expf(al[n]) * 1.44269504f;
            ap[n] = 1.f;
            bc[n] = 0.f;
        }
    }
    const int l0 = c * CHLEN;
    for (int l = l0; l < l0 + CHLEN; ++l) {
        const float dtv = b2f(dtb[(size_t)l * DI + d]);
        const float xsv = b2f(xsb[(size_t)l * DI + d]);
        const float dx = dtv * xsv;
        float bv[NS];
#pragma unroll
        for (int q = 0; q < 4; q++)
            *(float4*)&bv[q * 4] = *(const float4*)&xdbl[(size_t)l * NXDBL + DTR + q * 4];
#pragma unroll
        for (int n = 0; n < NS; n++) {
            const float al = __builtin_amdgcn_exp2f(dtv * An2[n]);
            ap[n] *= al;
            bc[n] = fmaf(al, bc[n], dx * bv[n]);
        }
    }
    const size_t o = ((size_t)c * DI + d) * NS;
#pragma unroll
    for (int q = 0; q < 4; q++) {
        *(float4*)&chA[o + q * 4] = *(float4*)&ap[q * 4];
        *(float4*)&chB[o + q * 4] = *(float4*)&bc[q * 4];
    }
}

// ---------------- scan phase 2: serial prefix over chunks (h0 in-place in chA) ---
__global__ __launch_bounds__(256) void scan_phase2(float* __restrict__ chA,
                                                   const float* __restrict__ chB,
                                                   float* __restrict__ hT_out) {
    const int t = blockIdx.x * 256 + threadIdx.x;  // 0..DI*NS-1
    float h = 0.f;
#pragma unroll 4
    for (int c = 0; c < NCHUNK; ++c) {
        const size_t o = (size_t)c * DI * NS + t;
        const float a = chA[o];
        const float b = chB[o];
        chA[o] = h;
        h = fmaf(a, h, b);
    }
    hT_out[t] = h;
}

// ---------------- scan phase 3: re-scan with h0, fused y epilogue (bf16 y) -------
__global__ __launch_bounds__(256) void scan_phase3(const u16* __restrict__ dtb,
                                                   const u16* __restrict__ xsb,
                                                   const float* __restrict__ xdbl,
                                                   const float* __restrict__ A_log,
                                                   const float* __restrict__ h0,
                                                   const float* __restrict__ Dw,
                                                   const u16* __restrict__ gate,
                                                   u16* __restrict__ yb) {
    const int g = blockIdx.x * 256 + threadIdx.x;
    const int d = g & (DI - 1);
    const int c = g >> 11;
    float An2[NS], h[NS];
    {
        float al[NS];
#pragma unroll
        for (int q = 0; q < 4; q++)
            *(float4*)&al[q * 4] = *(const float4*)&A_log[d * NS + q * 4];
#pragma unroll
        for (int n = 0; n < NS; n++) An2[n] = -__expf(al[n]) * 1.44269504f;
    }
    const size_t ho = ((size_t)c * DI + d) * NS;
#pragma unroll
    for (int q = 0; q < 4; q++) *(float4*)&h[q * 4] = *(const float4*)&h0[ho + q * 4];
    const float Dd = Dw[d];
    const int l0 = c * CHLEN;
    for (int l = l0; l < l0 + CHLEN; ++l) {
        const float dtv = b2f(dtb[(size_t)l * DI + d]);
        const float xsv = b2f(xsb[(size_t)l * DI + d]);
        const float gv = b2f(gate[(size_t)l * DI + d]);
        const float dx = dtv * xsv;
        float bv[NS], cv[NS];
#pragma unroll
        for (int q = 0; q < 4; q++) {
            *(float4*)&bv[q * 4] = *(const float4*)&xdbl[(size_t)l * NXDBL + DTR + q * 4];
            *(float4*)&cv[q * 4] =
                *(const float4*)&xdbl[(size_t)l * NXDBL + DTR + NS + q * 4];
        }
#pragma unroll
        for (int n = 0; n < NS; n++) {
            const float al = __builtin_amdgcn_exp2f(dtv * An2[n]);
            h[n] = fmaf(al, h[n], dx * bv[n]);
        }
        float y0 = 0.f, y1 = 0.f, y2 = 0.f, y3 = 0.f;
#pragma unroll
        for (int n = 0; n < NS; n += 4) {
            y0 = fmaf(h[n + 0], cv[n + 0], y0);
            y1 = fmaf(h[n + 1], cv[n + 1], y1);
            y2 = fmaf(h[n + 2], cv[n + 2], y2);
            y3 = fmaf(h[n + 3], cv[n + 3], y3);
        }
        const float yv = (((y0 + y1) + (y2 + y3)) + xsv * Dd) * gv;
        yb[(size_t)l * DI + d] = f2b(yv);
    }
}

extern "C" void kernel_launch(void* const* d_in, const int* in_sizes, int n_in,
                              void* d_out, int out_size, void* d_ws, size_t ws_size,
                              hipStream_t stream) {
    const float* x = (const float*)d_in[0];
    const float* W_in = (const float*)d_in[1];
    const float* conv_w = (const float*)d_in[2];
    const float* conv_b = (const float*)d_in[3];
    const float* W_x = (const float*)d_in[4];
    const float* W_dt = (const float*)d_in[5];
    const float* b_dt = (const float*)d_in[6];
    const float* A_log = (const float*)d_in[7];
    const float* Dw = (const float*)d_in[8];
    const float* W_out = (const float*)d_in[9];
    float* out = (float*)d_out;

    // Flat workspace map (no aliasing), offsets in FLOATS.
    // L*DI bf16 buffers = 2097152 float-equivalents (8 MB). Total ~110 MB.
    float* ws = (float*)d_ws;
    u16*   xcb      = (u16*)(ws + 0);         // L*DI bf16     (2097152 f)
    u16*   gate     = (u16*)(ws + 2097152);   // L*DI bf16     (2097152 f)
    u16*   xs_b     = (u16*)(ws + 4194304);   // L*DI bf16     (2097152 f)
    u16*   dtb      = (u16*)(ws + 6291456);   // L*DI bf16     (2097152 f)
    float* xdbl     = ws + 8388608;           // L*96 f32      (196608 f)
    float* chA      = ws + 8585216;           // NCHUNK*DI*NS  (2097152 f, ->h0)
    float* chB      = ws + 10682368;          // NCHUNK*DI*NS  (2097152 f)
    u16*   xb       = (u16*)(ws + 12779520);  // L*DM bf16     (1048576 f)
    u16*   W_inT_b  = (u16*)(ws + 13828096);  // 2DI*DM bf16   (2097152 f)
    u16*   W_outT_b = (u16*)(ws + 15925248);  // DM*DI bf16    (1048576 f)
    u16*   W_xT_pad = (u16*)(ws + 16973824);  // 128*DI bf16   (131072 f)
    float* g2part   = ws + 17104896;          // 16*L*128 f32  (4194304 f)
    float* g4part   = ws + 21299200;          // 2*L*DM f32    (4194304 f)
    u16*   yb       = (u16*)(ws + 25493504);  // L*DI bf16     (2097152 f)

    // 1) bf16 converts for GEMM1
    convert_plain<<<(LL * DM) / 1024, 256, 0, stream>>>(x, xb);
    convert_T<<<dim3(2 * DI / 32, DM / 32), 256, 0, stream>>>(W_in, W_inT_b, DM, 2 * DI);
    // 2) x_and_res = x @ W_in  (bf16 MFMA) -> xcb (bf16), gate = silu(res) (bf16)
    gemm_mfma<1, DM / 32><<<dim3(2 * DI / 128, LL / 128), 256, 0, stream>>>(
        xb, W_inT_b, xcb, gate, LL, 2 * DI, DM);
    // 3) conv + silu -> xs_b (bf16)
    conv_silu<<<(LL * DI) / 256, 256, 0, stream>>>(xcb, conv_w, conv_b, xs_b);
    // 4) W_x -> [96][DI] bf16, rows 96..127 zeroed
    fill_zero_u16<<<(32 * DI + 255) / 256, 256, 0, stream>>>(W_xT_pad + 96 * DI, 32 * DI);
    convert_T<<<dim3(NXDBL / 32, DI / 32), 256, 0, stream>>>(W_x, W_xT_pad, DI, NXDBL);
    // 5) x_dbl = xs @ W_x  (bf16 MFMA, split-K=16 over z, N padded to 128)
    gemm_mfma<0, 4><<<dim3(1, LL / 128, 16), 256, 0, stream>>>(
        xs_b, W_xT_pad, g2part, nullptr, LL, 128, DI);
    g2reduce<<<(LL * NXDBL + 255) / 256, 256, 0, stream>>>(g2part, xdbl);
    // 6) dt = softplus(dt_r @ W_dt + b_dt)  (fp32 128^2 8x8, bf16 out)
    gemm128_dt<<<dim3(DI / 128, LL / 128), 256, 0, stream>>>(xdbl, W_dt, b_dt, dtb,
                                                             DI, DTR, NXDBL);
    // 7) chunked scan
    scan_phase1<<<(DI * NCHUNK) / 256, 256, 0, stream>>>(dtb, xs_b, xdbl, A_log,
                                                         chA, chB);
    scan_phase2<<<(DI * NS) / 256, 256, 0, stream>>>(chA, chB, out + (size_t)LL * DM);
    // 8) W_out convert + scan phase 3 -> yb (bf16)
    convert_T<<<dim3(DM / 32, DI / 32), 256, 0, stream>>>(W_out, W_outT_b, DI, DM);
    scan_phase3<<<(DI * NCHUNK) / 256, 256, 0, stream>>>(dtb, xs_b, xdbl, A_log, chA,
                                                         Dw, gate, yb);
    // 9) out = y @ W_out (bf16 MFMA, split-K=2 over z)
    gemm_mfma<0, DI / 64><<<dim3(DM / 128, LL / 128, 2), 256, 0, stream>>>(
        yb, W_outT_b, g4part, nullptr, LL, DM, DI);
    sum2<<<(LL * DM) / 1024, 256, 0, stream>>>(g4part, out, LL * DM);
}

// Round 10
// 178.732 us; speedup vs baseline: 1.1531x; 1.1531x over previous
//
#include <hip/hip_runtime.h>
#include <math.h>

#define DM 1024
#define DI 2048
#define NS 16
#define DTR 64
#define LL 2048
#define NXDBL 96      // DTR + 2*NS
#define NCHUNK 128
#define CHLEN 16      // LL / NCHUNK

typedef unsigned short u16;
typedef __attribute__((ext_vector_type(8))) short short8;
typedef __attribute__((ext_vector_type(4))) float f32x4;

__device__ __forceinline__ float sigmoidf_(float x) { return 1.f / (1.f + __expf(-x)); }
__device__ __forceinline__ float siluf_(float x) { return x * sigmoidf_(x); }
__device__ __forceinline__ float softplus_fast(float x) {
    return fmaxf(x, 0.f) + __logf(1.f + __expf(-fabsf(x)));
}
__device__ __forceinline__ u16 f2b(float f) {  // fp32 -> bf16 RNE
    unsigned u = __float_as_uint(f);
    return (u16)((u + 0x7FFFu + ((u >> 16) & 1u)) >> 16);
}

// ---------------- fp32 -> bf16 plain convert (4 elems/thread) -----------------
__global__ __launch_bounds__(256) void convert_plain(const float* __restrict__ src,
                                                     u16* __restrict__ dst) {
    const int i = (blockIdx.x * 256 + threadIdx.x) * 4;
    float4 v = *(const float4*)&src[i];
    u16 o[4] = {f2b(v.x), f2b(v.y), f2b(v.z), f2b(v.w)};
    *(ushort4*)&dst[i] = *(ushort4*)o;
}

// ---------------- fp32 [R][C] -> bf16 [C][R] transpose convert -----------------
__global__ __launch_bounds__(256) void convert_T(const float* __restrict__ src,
                                                 u16* __restrict__ dst, int R, int C) {
    __shared__ float t[32][33];
    const int tx = threadIdx.x & 31, ty = threadIdx.x >> 5;  // ty 0..7
    const int c0 = blockIdx.x * 32, r0 = blockIdx.y * 32;
#pragma unroll
    for (int i = 0; i < 4; i++)
        t[ty + i * 8][tx] = src[(size_t)(r0 + ty + i * 8) * C + c0 + tx];
    __syncthreads();
#pragma unroll
    for (int i = 0; i < 4; i++)
        dst[(size_t)(c0 + ty + i * 8) * R + r0 + tx] = f2b(t[tx][ty + i * 8]);
}

__global__ __launch_bounds__(256) void fill_zero_u16(u16* __restrict__ p, int n) {
    const int i = blockIdx.x * 256 + threadIdx.x;
    if (i < n) p[i] = 0;
}

// ---------------- bf16 MFMA GEMM: C[M][N] = A[M][K] @ Bt[N][K]^T -----------------
// 128x128 tile, BK=32, K = NSTEPS*32. 3-buffer LDS pipeline, prefetch distance 2,
// counted s_waitcnt vmcnt(N) + raw s_barrier. LDS k-group XOR swizzle
// (kg' = kg ^ ((row>>1)&3)) on the per-lane GLOBAL source (write) and the
// ds_read offset (read); LDS stays linear for global_load_lds.
// EPI==1: split cols [0,DI)->C0, [DI,2DI)->C1, both ld=DI.
// EPI==0: fp32 partial to C0 + blockIdx.z*M*N (split-K over gridDim.z).
#define WAITV(N) asm volatile("s_waitcnt vmcnt(" #N ")" ::: "memory")
template <int EPI, int NSTEPS>
__global__ __launch_bounds__(256) void gemm_mfma(const u16* __restrict__ A,
                                                 const u16* __restrict__ Bt,
                                                 float* __restrict__ C0,
                                                 float* __restrict__ C1,
                                                 int M, int N, int lda) {
    __shared__ u16 As[3][128 * 32];
    __shared__ u16 Bs[3][128 * 32];
    const int tid = threadIdx.x;
    const int lane = tid & 63;
    const int wave = tid >> 6;
    const int bm = blockIdx.y * 128, bn = blockIdx.x * 128;
    const int wr = wave >> 1, wc = wave & 1;
    const int k_off = blockIdx.z * (NSTEPS * 32);

    f32x4 acc[4][4];
#pragma unroll
    for (int m = 0; m < 4; m++)
#pragma unroll
        for (int n = 0; n < 4; n++) acc[m][n] = (f32x4)0.f;

    // staging: thread tid -> (row = tid>>2, kg = tid&3), LDS linear at tid*16B.
    const int srow = tid >> 2;
    const int swz = (tid >> 3) & 3;                    // (srow>>1)&3
    const int skel = (((tid & 3) ^ swz) << 3);         // swizzled k elem offset
    const u16* Ag0 = A + (size_t)(bm + srow) * lda + k_off + skel;
    const u16* Ag1 = A + (size_t)(bm + 64 + srow) * lda + k_off + skel;
    const u16* Bg0 = Bt + (size_t)(bn + srow) * lda + k_off + skel;
    const u16* Bg1 = Bt + (size_t)(bn + 64 + srow) * lda + k_off + skel;
    u16* Asl = &As[0][0] + tid * 8;
    u16* Bsl = &Bs[0][0] + tid * 8;

    // fragment read offsets (u16 units), same swizzle on the kg index
    const int rsw = (lane >> 1) & 3;                   // row bits 1-2
    const int arow = (wr * 64 + (lane & 15)) * 32 + (((lane >> 4) ^ rsw) << 3);
    const int brow = (wc * 64 + (lane & 15)) * 32 + (((lane >> 4) ^ rsw) << 3);

#define STAGE(buf, ks)                                                               \
    do {                                                                             \
        __builtin_amdgcn_global_load_lds(                                            \
            (const __attribute__((address_space(1))) unsigned*)(Ag0 + (ks)),         \
            (__attribute__((address_space(3))) unsigned*)(Asl + (buf) * 4096),       \
            16, 0, 0);                                                               \
        __builtin_amdgcn_global_load_lds(                                            \
            (const __attribute__((address_space(1))) unsigned*)(Ag1 + (ks)),         \
            (__attribute__((address_space(3))) unsigned*)(Asl + (buf) * 4096 + 2048),\
            16, 0, 0);                                                               \
        __builtin_amdgcn_global_load_lds(                                            \
            (const __attribute__((address_space(1))) unsigned*)(Bg0 + (ks)),         \
            (__attribute__((address_space(3))) unsigned*)(Bsl + (buf) * 4096),       \
            16, 0, 0);                                                               \
        __builtin_amdgcn_global_load_lds(                                            \
            (const __attribute__((address_space(1))) unsigned*)(Bg1 + (ks)),         \
            (__attribute__((address_space(3))) unsigned*)(Bsl + (buf) * 4096 + 2048),\
            16, 0, 0);                                                               \
    } while (0)

#define COMPUTE(buf)                                                                 \
    do {                                                                             \
        short8 av[4], bv[4];                                                         \
        _Pragma("unroll") for (int m = 0; m < 4; m++)                                \
            av[m] = *(const short8*)&As[buf][arow + m * 512];                        \
        _Pragma("unroll") for (int n = 0; n < 4; n++)                                \
            bv[n] = *(const short8*)&Bs[buf][brow + n * 512];                        \
        _Pragma("unroll") for (int m = 0; m < 4; m++)                                \
            _Pragma("unroll") for (int n = 0; n < 4; n++)                            \
                acc[m][n] = __builtin_amdgcn_mfma_f32_16x16x32_bf16(av[m], bv[n],    \
                                                                    acc[m][n], 0, 0, 0); \
    } while (0)

    STAGE(0, 0);
    if (NSTEPS > 1) STAGE(1, 32);
#pragma unroll
    for (int s = 0; s < NSTEPS; ++s) {
        if (s + 2 < NSTEPS) {
            STAGE((s + 2) % 3, (s + 2) * 32);
            WAITV(8);                      // oldest 4 (tile s) complete; 8 in flight
        } else if (s + 1 < NSTEPS) {
            WAITV(4);
        } else {
            WAITV(0);
        }
        __builtin_amdgcn_s_barrier();      // tile s visible to all waves
        COMPUTE(s % 3);
        __builtin_amdgcn_s_barrier();      // reads done before buf reuse
    }
#undef STAGE
#undef COMPUTE

    const int crow0 = bm + wr * 64 + (lane >> 4) * 4;
    const int ccol0 = bn + wc * 64 + (lane & 15);
    float* C0z = C0 + (size_t)blockIdx.z * M * N;
#pragma unroll
    for (int m = 0; m < 4; m++)
#pragma unroll
        for (int n = 0; n < 4; n++) {
            const int col = ccol0 + n * 16;
#pragma unroll
            for (int r = 0; r < 4; r++) {
                const int row = crow0 + m * 16 + r;
                const float v = acc[m][n][r];
                if (EPI == 1) {
                    if (col < DI)
                        C0[(size_t)row * DI + col] = v;
                    else
                        C1[(size_t)row * DI + col - DI] = v;
                } else {
                    C0z[(size_t)row * N + col] = v;
                }
            }
        }
}

// ---------------- fp32 GEMM 128x128 tile, 8x8 micro, BK=16: dt path (K=64) -------
__global__ __launch_bounds__(256) void gemm128_dt(const float* __restrict__ A,
                                                  const float* __restrict__ B,
                                                  const float* __restrict__ bias,
                                                  float* __restrict__ C,
                                                  int N, int K, int lda) {
    __shared__ float As[16][128];
    __shared__ float Bs[16][128];
    const int tid = threadIdx.x;
    const int bm = blockIdx.y * 128, bn = blockIdx.x * 128;
    const int ty = tid >> 4, tx = tid & 15;
    float acc[8][8];
#pragma unroll
    for (int i = 0; i < 8; i++)
#pragma unroll
        for (int j = 0; j < 8; j++) acc[i][j] = 0.f;

    const int ar = tid >> 2, ak = (tid & 3) << 2;
    const int bk = tid >> 5, bc = (tid & 31) << 2;

    for (int k0 = 0; k0 < K; k0 += 16) {
        float4 a0 = *(const float4*)&A[(size_t)(bm + ar) * lda + k0 + ak];
        float4 a1 = *(const float4*)&A[(size_t)(bm + ar + 64) * lda + k0 + ak];
        float4 b0 = *(const float4*)&B[(size_t)(k0 + bk) * N + bn + bc];
        float4 b1 = *(const float4*)&B[(size_t)(k0 + bk + 8) * N + bn + bc];
        __syncthreads();
        As[ak + 0][ar] = a0.x; As[ak + 1][ar] = a0.y;
        As[ak + 2][ar] = a0.z; As[ak + 3][ar] = a0.w;
        As[ak + 0][ar + 64] = a1.x; As[ak + 1][ar + 64] = a1.y;
        As[ak + 2][ar + 64] = a1.z; As[ak + 3][ar + 64] = a1.w;
        *(float4*)&Bs[bk][bc] = b0;
        *(float4*)&Bs[bk + 8][bc] = b1;
        __syncthreads();
#pragma unroll
        for (int k = 0; k < 16; k++) {
            float a[8], b[8];
            *(float4*)&a[0] = *(const float4*)&As[k][ty * 8];
            *(float4*)&a[4] = *(const float4*)&As[k][ty * 8 + 4];
            *(float4*)&b[0] = *(const float4*)&Bs[k][tx * 8];
            *(float4*)&b[4] = *(const float4*)&Bs[k][tx * 8 + 4];
#pragma unroll
            for (int i = 0; i < 8; i++)
#pragma unroll
                for (int j = 0; j < 8; j++) acc[i][j] = fmaf(a[i], b[j], acc[i][j]);
        }
    }
#pragma unroll
    for (int i = 0; i < 8; i++) {
        const int row = bm + ty * 8 + i;
#pragma unroll
        for (int j = 0; j < 8; j += 4) {
            const int col = bn + tx * 8 + j;
            const float4 bi = *(const float4*)&bias[col];
            float4 v = make_float4(softplus_fast(acc[i][j] + bi.x),
                                   softplus_fast(acc[i][j + 1] + bi.y),
                                   softplus_fast(acc[i][j + 2] + bi.z),
                                   softplus_fast(acc[i][j + 3] + bi.w));
            *(float4*)&C[(size_t)row * N + col] = v;
        }
    }
}

// ---------------- sum of 2 split-K partials -----------------
__global__ __launch_bounds__(256) void sum2(const float* __restrict__ p,
                                            float* __restrict__ out, int n) {
    const int i = (blockIdx.x * 256 + threadIdx.x) * 4;
    float4 a = *(const float4*)&p[i];
    float4 b = *(const float4*)&p[(size_t)n + i];
    *(float4*)&out[i] = make_float4(a.x + b.x, a.y + b.y, a.z + b.z, a.w + b.w);
}

// ---------------- reduce 16 split-K partials [z][L][128] -> xdbl [L][96] ---------
__global__ __launch_bounds__(256) void g2reduce(const float* __restrict__ part,
                                                float* __restrict__ xdbl) {
    const int gid = blockIdx.x * 256 + threadIdx.x;
    if (gid < LL * NXDBL) {
        const int row = gid / NXDBL;
        const int col = gid - row * NXDBL;
        float s = 0.f;
#pragma unroll
        for (int z = 0; z < 16; z++) s += part[((size_t)z * LL + row) * 128 + col];
        xdbl[gid] = s;
    }
}

// ---------------- conv (k=4, causal) + silu -> xs (f32) + xs_b (bf16) ------------
__global__ __launch_bounds__(256) void conv_silu(const float* __restrict__ xc,
                                                 const float* __restrict__ cw,
                                                 const float* __restrict__ cb,
                                                 float* __restrict__ xs,
                                                 u16* __restrict__ xsb) {
    const int gid = blockIdx.x * 256 + threadIdx.x;  // l*DI + d
    const int l = gid >> 11;
    const int d = gid & (DI - 1);
    const float4 w = *(const float4*)&cw[d * 4];
    float acc = cb[d];
    const float wj[4] = {w.x, w.y, w.z, w.w};
#pragma unroll
    for (int j = 0; j < 4; j++) {
        const int li = l + j - 3;
        if (li >= 0) acc = fmaf(xc[(size_t)li * DI + d], wj[j], acc);
    }
    const float s = siluf_(acc);
    xs[gid] = s;
    xsb[gid] = f2b(s);
}

// ---------------- scan phase 1: per-chunk composition, 16 states/thread ---------
__global__ __launch_bounds__(256) void scan_phase1(const float* __restrict__ dt,
                                                   const float* __restrict__ xs,
                                                   const float* __restrict__ xdbl,
                                                   const float* __restrict__ A_log,
                                                   float* __restrict__ chA,
                                                   float* __restrict__ chB) {
    const int g = blockIdx.x * 256 + threadIdx.x;
    const int d = g & (DI - 1);
    const int c = g >> 11;
    float An2[NS], ap[NS], bc[NS];
    {
        float al[NS];
#pragma unroll
        for (int q = 0; q < 4; q++)
            *(float4*)&al[q * 4] = *(const float4*)&A_log[d * NS + q * 4];
#pragma unroll
        for (int n = 0; n < NS; n++) {
            An2[n] = -__expf(al[n]) * 1.44269504f;
            ap[n] = 1.f;
            bc[n] = 0.f;
        }
    }
    const int l0 = c * CHLEN;
    for (int l = l0; l < l0 + CHLEN; ++l) {
        const float dtv = dt[(size_t)l * DI + d];
        const float xsv = xs[(size_t)l * DI + d];
        const float dx = dtv * xsv;
        float bv[NS];
#pragma unroll
        for (int q = 0; q < 4; q++)
            *(float4*)&bv[q * 4] = *(const float4*)&xdbl[(size_t)l * NXDBL + DTR + q * 4];
#pragma unroll
        for (int n = 0; n < NS; n++) {
            const float al = __builtin_amdgcn_exp2f(dtv * An2[n]);
            ap[n] *= al;
            bc[n] = fmaf(al, bc[n], dx * bv[n]);
        }
    }
    const size_t o = ((size_t)c * DI + d) * NS;
#pragma unroll
    for (int q = 0; q < 4; q++) {
        *(float4*)&chA[o + q * 4] = *(float4*)&ap[q * 4];
        *(float4*)&chB[o + q * 4] = *(float4*)&bc[q * 4];
    }
}

// ---------------- scan phase 2: serial prefix over chunks (h0 in-place in chA) ---
__global__ __launch_bounds__(256) void scan_phase2(float* __restrict__ chA,
                                                   const float* __restrict__ chB,
                                                   float* __restrict__ hT_out) {
    const int t = blockIdx.x * 256 + threadIdx.x;  // 0..DI*NS-1
    float h = 0.f;
#pragma unroll 4
    for (int c = 0; c < NCHUNK; ++c) {
        const size_t o = (size_t)c * DI * NS + t;
        const float a = chA[o];
        const float b = chB[o];
        chA[o] = h;
        h = fmaf(a, h, b);
    }
    hT_out[t] = h;
}

// ---------------- scan phase 3: re-scan with h0, fused y epilogue (bf16 y) -------
__global__ __launch_bounds__(256) void scan_phase3(const float* __restrict__ dt,
                                                   const float* __restrict__ xs,
                                                   const float* __restrict__ xdbl,
                                                   const float* __restrict__ A_log,
                                                   const float* __restrict__ h0,
                                                   const float* __restrict__ Dw,
                                                   const float* __restrict__ res,
                                                   u16* __restrict__ yb) {
    const int g = blockIdx.x * 256 + threadIdx.x;
    const int d = g & (DI - 1);
    const int c = g >> 11;
    float An2[NS], h[NS];
    {
        float al[NS];
#pragma unroll
        for (int q = 0; q < 4; q++)
            *(float4*)&al[q * 4] = *(const float4*)&A_log[d * NS + q * 4];
#pragma unroll
        for (int n = 0; n < NS; n++) An2[n] = -__expf(al[n]) * 1.44269504f;
    }
    const size_t ho = ((size_t)c * DI + d) * NS;
#pragma unroll
    for (int q = 0; q < 4; q++) *(float4*)&h[q * 4] = *(const float4*)&h0[ho + q * 4];
    const float Dd = Dw[d];
    const int l0 = c * CHLEN;
    for (int l = l0; l < l0 + CHLEN; ++l) {
        const float dtv = dt[(size_t)l * DI + d];
        const float xsv = xs[(size_t)l * DI + d];
        const float resv = res[(size_t)l * DI + d];
        const float dx = dtv * xsv;
        float bv[NS], cv[NS];
#pragma unroll
        for (int q = 0; q < 4; q++) {
            *(float4*)&bv[q * 4] = *(const float4*)&xdbl[(size_t)l * NXDBL + DTR + q * 4];
            *(float4*)&cv[q * 4] =
                *(const float4*)&xdbl[(size_t)l * NXDBL + DTR + NS + q * 4];
        }
#pragma unroll
        for (int n = 0; n < NS; n++) {
            const float al = __builtin_amdgcn_exp2f(dtv * An2[n]);
            h[n] = fmaf(al, h[n], dx * bv[n]);
        }
        float y0 = 0.f, y1 = 0.f, y2 = 0.f, y3 = 0.f;
#pragma unroll
        for (int n = 0; n < NS; n += 4) {
            y0 = fmaf(h[n + 0], cv[n + 0], y0);
            y1 = fmaf(h[n + 1], cv[n + 1], y1);
            y2 = fmaf(h[n + 2], cv[n + 2], y2);
            y3 = fmaf(h[n + 3], cv[n + 3], y3);
        }
        float yv = ((y0 + y1) + (y2 + y3)) + xsv * Dd;
        yv *= siluf_(resv);
        yb[(size_t)l * DI + d] = f2b(yv);
    }
}

extern "C" void kernel_launch(void* const* d_in, const int* in_sizes, int n_in,
                              void* d_out, int out_size, void* d_ws, size_t ws_size,
                              hipStream_t stream) {
    const float* x = (const float*)d_in[0];
    const float* W_in = (const float*)d_in[1];
    const float* conv_w = (const float*)d_in[2];
    const float* conv_b = (const float*)d_in[3];
    const float* W_x = (const float*)d_in[4];
    const float* W_dt = (const float*)d_in[5];
    const float* b_dt = (const float*)d_in[6];
    const float* A_log = (const float*)d_in[7];
    const float* Dw = (const float*)d_in[8];
    const float* W_out = (const float*)d_in[9];
    float* out = (float*)d_out;

    // Flat workspace map (no aliasing), offsets in FLOATS. NCHUNK=128:
    // chA/chB = NCHUNK*DI*NS = 4194304 floats (16.8 MB) each. Total ~169 MB.
    float* ws = (float*)d_ws;
    float* xc       = ws;                     // L*DI f32      (4194304)
    float* res      = ws + 4194304;           // L*DI f32      (4194304)
    float* xs       = ws + 8388608;           // L*DI f32      (4194304)
    float* dt       = ws + 12582912;          // L*DI f32      (4194304)
    float* xdbl     = ws + 16777216;          // L*96 f32      (196608)
    float* chA      = ws + 16973824;          // NCHUNK*DI*NS  (4194304, ->h0)
    float* chB      = ws + 21168128;          // NCHUNK*DI*NS  (4194304)
    u16*   xb       = (u16*)(ws + 25362432);  // L*DM bf16     (1048576 f)
    u16*   W_inT_b  = (u16*)(ws + 26411008);  // 2DI*DM bf16   (2097152 f)
    u16*   W_outT_b = (u16*)(ws + 28508160);  // DM*DI bf16    (1048576 f)
    u16*   xs_b     = (u16*)(ws + 29556736);  // L*DI bf16     (2097152 f)
    u16*   W_xT_pad = (u16*)(ws + 31653888);  // 128*DI bf16   (131072 f)
    float* g2part   = ws + 31784960;          // 16*L*128 f32  (4194304 f)
    float* g4part   = ws + 35979264;          // 2*L*DM f32    (4194304 f)
    u16*   yb       = (u16*)(ws + 40173568);  // L*DI bf16     (2097152 f)

    // 1) bf16 converts for GEMM1
    convert_plain<<<(LL * DM) / 1024, 256, 0, stream>>>(x, xb);
    convert_T<<<dim3(2 * DI / 32, DM / 32), 256, 0, stream>>>(W_in, W_inT_b, DM, 2 * DI);
    // 2) x_and_res = x @ W_in  (bf16 MFMA) -> xc, res
    gemm_mfma<1, DM / 32><<<dim3(2 * DI / 128, LL / 128), 256, 0, stream>>>(
        xb, W_inT_b, xc, res, LL, 2 * DI, DM);
    // 3) conv + silu -> xs (f32) + xs_b (bf16)
    conv_silu<<<(LL * DI) / 256, 256, 0, stream>>>(xc, conv_w, conv_b, xs, xs_b);
    // 4) W_x -> [96][DI] bf16, rows 96..127 zeroed
    fill_zero_u16<<<(32 * DI + 255) / 256, 256, 0, stream>>>(W_xT_pad + 96 * DI, 32 * DI);
    convert_T<<<dim3(NXDBL / 32, DI / 32), 256, 0, stream>>>(W_x, W_xT_pad, DI, NXDBL);
    // 5) x_dbl = xs @ W_x  (bf16 MFMA, split-K=16 over z, N padded to 128)
    gemm_mfma<0, 4><<<dim3(1, LL / 128, 16), 256, 0, stream>>>(
        xs_b, W_xT_pad, g2part, nullptr, LL, 128, DI);
    g2reduce<<<(LL * NXDBL + 255) / 256, 256, 0, stream>>>(g2part, xdbl);
    // 6) dt = softplus(dt_r @ W_dt + b_dt)  (fp32 128^2 8x8)
    gemm128_dt<<<dim3(DI / 128, LL / 128), 256, 0, stream>>>(xdbl, W_dt, b_dt, dt,
                                                             DI, DTR, NXDBL);
    // 7) chunked scan (NCHUNK=128 -> 1024 blocks for phase1/3)
    scan_phase1<<<(DI * NCHUNK) / 256, 256, 0, stream>>>(dt, xs, xdbl, A_log, chA, chB);
    scan_phase2<<<(DI * NS) / 256, 256, 0, stream>>>(chA, chB, out + (size_t)LL * DM);
    // 8) W_out convert + scan phase 3 -> yb (bf16)
    convert_T<<<dim3(DM / 32, DI / 32), 256, 0, stream>>>(W_out, W_outT_b, DI, DM);
    scan_phase3<<<(DI * NCHUNK) / 256, 256, 0, stream>>>(dt, xs, xdbl, A_log, chA, Dw,
                                                         res, yb);
    // 9) out = y @ W_out (bf16 MFMA, split-K=2 over z)
    gemm_mfma<0, DI / 64><<<dim3(DM / 128, LL / 128, 2), 256, 0, stream>>>(
        yb, W_outT_b, g4part, nullptr, LL, DM, DI);
    sum2<<<(LL * DM) / 1024, 256, 0, stream>>>(g4part, out, LL * DM);
}

// Round 11
// 171.730 us; speedup vs baseline: 1.2001x; 1.0408x over previous
//
#include <hip/hip_runtime.h>
#include <math.h>

#define DM 1024
#define DI 2048
#define NS 16
#define DTR 64
#define LL 2048
#define NXDBL 96      // DTR + 2*NS
#define NCHUNK 128
#define CHLEN 16      // LL / NCHUNK

typedef unsigned short u16;
typedef __attribute__((ext_vector_type(8))) short short8;
typedef __attribute__((ext_vector_type(4))) float f32x4;

__device__ __forceinline__ float sigmoidf_(float x) { return 1.f / (1.f + __expf(-x)); }
__device__ __forceinline__ float siluf_(float x) { return x * sigmoidf_(x); }
__device__ __forceinline__ float softplus_fast(float x) {
    return fmaxf(x, 0.f) + __logf(1.f + __expf(-fabsf(x)));
}
__device__ __forceinline__ u16 f2b(float f) {  // fp32 -> bf16 RNE
    unsigned u = __float_as_uint(f);
    return (u16)((u + 0x7FFFu + ((u >> 16) & 1u)) >> 16);
}

// ---------------- fused prep: x->bf16, W_in^T, W_out^T, W_x^T + zero-pad --------
__device__ __forceinline__ void convT_dev(const float* __restrict__ src,
                                          u16* __restrict__ dst, int R, int C,
                                          int bflat, int gridx, float (*t)[33]) {
    const int tx = threadIdx.x & 31, ty = threadIdx.x >> 5;  // ty 0..7
    const int c0 = (bflat % gridx) * 32, r0 = (bflat / gridx) * 32;
#pragma unroll
    for (int i = 0; i < 4; i++)
        t[ty + i * 8][tx] = src[(size_t)(r0 + ty + i * 8) * C + c0 + tx];
    __syncthreads();
#pragma unroll
    for (int i = 0; i < 4; i++)
        dst[(size_t)(c0 + ty + i * 8) * R + r0 + tx] = f2b(t[tx][ty + i * 8]);
}

// block ranges: [0,2048) x-convert | [2048,6144) W_in^T | [6144,8192) W_out^T |
//               [8192,8384) W_x^T | [8384,8640) zero-pad rows 96..127
#define PREP_BLOCKS 8640
__global__ __launch_bounds__(256) void prep_all(const float* __restrict__ x,
                                                u16* __restrict__ xb,
                                                const float* __restrict__ W_in,
                                                u16* __restrict__ W_inT,
                                                const float* __restrict__ W_out,
                                                u16* __restrict__ W_outT,
                                                const float* __restrict__ W_x,
                                                u16* __restrict__ W_xT_pad) {
    __shared__ float t[32][33];
    const int b = blockIdx.x;
    if (b < 2048) {
        const int i = (b * 256 + threadIdx.x) * 4;
        float4 v = *(const float4*)&x[i];
        u16 o[4] = {f2b(v.x), f2b(v.y), f2b(v.z), f2b(v.w)};
        *(ushort4*)&xb[i] = *(ushort4*)o;
    } else if (b < 6144) {
        convT_dev(W_in, W_inT, DM, 2 * DI, b - 2048, 2 * DI / 32, t);
    } else if (b < 8192) {
        convT_dev(W_out, W_outT, DI, DM, b - 6144, DM / 32, t);
    } else if (b < 8384) {
        convT_dev(W_x, W_xT_pad, DI, NXDBL, b - 8192, NXDBL / 32, t);
    } else {
        const int i = (b - 8384) * 256 + threadIdx.x;
        if (i < 32 * DI) W_xT_pad[96 * DI + i] = 0;
    }
}

// ---------------- bf16 MFMA GEMM: C[M][N] = A[M][K] @ Bt[N][K]^T -----------------
// 128x128 tile, BK=32, K = NSTEPS*32. 3-buffer LDS pipeline, prefetch distance 2,
// counted s_waitcnt vmcnt(N) + raw s_barrier. LDS k-group XOR swizzle
// (kg' = kg ^ ((row>>1)&3)) on the per-lane GLOBAL source (write) and the
// ds_read offset (read); LDS stays linear for global_load_lds.
// EPI==1: split cols [0,DI)->C0, [DI,2DI)->C1, both ld=DI.
// EPI==0: fp32 partial to C0 + blockIdx.z*M*N (split-K over gridDim.z).
#define WAITV(N) asm volatile("s_waitcnt vmcnt(" #N ")" ::: "memory")
template <int EPI, int NSTEPS>
__global__ __launch_bounds__(256) void gemm_mfma(const u16* __restrict__ A,
                                                 const u16* __restrict__ Bt,
                                                 float* __restrict__ C0,
                                                 float* __restrict__ C1,
                                                 int M, int N, int lda) {
    __shared__ u16 As[3][128 * 32];
    __shared__ u16 Bs[3][128 * 32];
    const int tid = threadIdx.x;
    const int lane = tid & 63;
    const int wave = tid >> 6;
    const int bm = blockIdx.y * 128, bn = blockIdx.x * 128;
    const int wr = wave >> 1, wc = wave & 1;
    const int k_off = blockIdx.z * (NSTEPS * 32);

    f32x4 acc[4][4];
#pragma unroll
    for (int m = 0; m < 4; m++)
#pragma unroll
        for (int n = 0; n < 4; n++) acc[m][n] = (f32x4)0.f;

    // staging: thread tid -> (row = tid>>2, kg = tid&3), LDS linear at tid*16B.
    const int srow = tid >> 2;
    const int swz = (tid >> 3) & 3;                    // (srow>>1)&3
    const int skel = (((tid & 3) ^ swz) << 3);         // swizzled k elem offset
    const u16* Ag0 = A + (size_t)(bm + srow) * lda + k_off + skel;
    const u16* Ag1 = A + (size_t)(bm + 64 + srow) * lda + k_off + skel;
    const u16* Bg0 = Bt + (size_t)(bn + srow) * lda + k_off + skel;
    const u16* Bg1 = Bt + (size_t)(bn + 64 + srow) * lda + k_off + skel;
    u16* Asl = &As[0][0] + tid * 8;
    u16* Bsl = &Bs[0][0] + tid * 8;

    // fragment read offsets (u16 units), same swizzle on the kg index
    const int rsw = (lane >> 1) & 3;                   // row bits 1-2
    const int arow = (wr * 64 + (lane & 15)) * 32 + (((lane >> 4) ^ rsw) << 3);
    const int brow = (wc * 64 + (lane & 15)) * 32 + (((lane >> 4) ^ rsw) << 3);

#define STAGE(buf, ks)                                                               \
    do {                                                                             \
        __builtin_amdgcn_global_load_lds(                                            \
            (const __attribute__((address_space(1))) unsigned*)(Ag0 + (ks)),         \
            (__attribute__((address_space(3))) unsigned*)(Asl + (buf) * 4096),       \
            16, 0, 0);                                                               \
        __builtin_amdgcn_global_load_lds(                                            \
            (const __attribute__((address_space(1))) unsigned*)(Ag1 + (ks)),         \
            (__attribute__((address_space(3))) unsigned*)(Asl + (buf) * 4096 + 2048),\
            16, 0, 0);                                                               \
        __builtin_amdgcn_global_load_lds(                                            \
            (const __attribute__((address_space(1))) unsigned*)(Bg0 + (ks)),         \
            (__attribute__((address_space(3))) unsigned*)(Bsl + (buf) * 4096),       \
            16, 0, 0);                                                               \
        __builtin_amdgcn_global_load_lds(                                            \
            (const __attribute__((address_space(1))) unsigned*)(Bg1 + (ks)),         \
            (__attribute__((address_space(3))) unsigned*)(Bsl + (buf) * 4096 + 2048),\
            16, 0, 0);                                                               \
    } while (0)

#define COMPUTE(buf)                                                                 \
    do {                                                                             \
        short8 av[4], bv[4];                                                         \
        _Pragma("unroll") for (int m = 0; m < 4; m++)                                \
            av[m] = *(const short8*)&As[buf][arow + m * 512];                        \
        _Pragma("unroll") for (int n = 0; n < 4; n++)                                \
            bv[n] = *(const short8*)&Bs[buf][brow + n * 512];                        \
        _Pragma("unroll") for (int m = 0; m < 4; m++)                                \
            _Pragma("unroll") for (int n = 0; n < 4; n++)                            \
                acc[m][n] = __builtin_amdgcn_mfma_f32_16x16x32_bf16(av[m], bv[n],    \
                                                                    acc[m][n], 0, 0, 0); \
    } while (0)

    STAGE(0, 0);
    if (NSTEPS > 1) STAGE(1, 32);
#pragma unroll
    for (int s = 0; s < NSTEPS; ++s) {
        if (s + 2 < NSTEPS) {
            STAGE((s + 2) % 3, (s + 2) * 32);
            WAITV(8);                      // oldest 4 (tile s) complete; 8 in flight
        } else if (s + 1 < NSTEPS) {
            WAITV(4);
        } else {
            WAITV(0);
        }
        __builtin_amdgcn_s_barrier();      // tile s visible to all waves
        COMPUTE(s % 3);
        __builtin_amdgcn_s_barrier();      // reads done before buf reuse
    }
#undef STAGE
#undef COMPUTE

    const int crow0 = bm + wr * 64 + (lane >> 4) * 4;
    const int ccol0 = bn + wc * 64 + (lane & 15);
    float* C0z = C0 + (size_t)blockIdx.z * M * N;
#pragma unroll
    for (int m = 0; m < 4; m++)
#pragma unroll
        for (int n = 0; n < 4; n++) {
            const int col = ccol0 + n * 16;
#pragma unroll
            for (int r = 0; r < 4; r++) {
                const int row = crow0 + m * 16 + r;
                const float v = acc[m][n][r];
                if (EPI == 1) {
                    if (col < DI)
                        C0[(size_t)row * DI + col] = v;
                    else
                        C1[(size_t)row * DI + col - DI] = v;
                } else {
                    C0z[(size_t)row * N + col] = v;
                }
            }
        }
}

// ---------------- fp32 GEMM 128x128 tile, 8x8 micro, BK=16: dt path (K=64) -------
__global__ __launch_bounds__(256) void gemm128_dt(const float* __restrict__ A,
                                                  const float* __restrict__ B,
                                                  const float* __restrict__ bias,
                                                  float* __restrict__ C,
                                                  int N, int K, int lda) {
    __shared__ float As[16][128];
    __shared__ float Bs[16][128];
    const int tid = threadIdx.x;
    const int bm = blockIdx.y * 128, bn = blockIdx.x * 128;
    const int ty = tid >> 4, tx = tid & 15;
    float acc[8][8];
#pragma unroll
    for (int i = 0; i < 8; i++)
#pragma unroll
        for (int j = 0; j < 8; j++) acc[i][j] = 0.f;

    const int ar = tid >> 2, ak = (tid & 3) << 2;
    const int bk = tid >> 5, bc = (tid & 31) << 2;

    for (int k0 = 0; k0 < K; k0 += 16) {
        float4 a0 = *(const float4*)&A[(size_t)(bm + ar) * lda + k0 + ak];
        float4 a1 = *(const float4*)&A[(size_t)(bm + ar + 64) * lda + k0 + ak];
        float4 b0 = *(const float4*)&B[(size_t)(k0 + bk) * N + bn + bc];
        float4 b1 = *(const float4*)&B[(size_t)(k0 + bk + 8) * N + bn + bc];
        __syncthreads();
        As[ak + 0][ar] = a0.x; As[ak + 1][ar] = a0.y;
        As[ak + 2][ar] = a0.z; As[ak + 3][ar] = a0.w;
        As[ak + 0][ar + 64] = a1.x; As[ak + 1][ar + 64] = a1.y;
        As[ak + 2][ar + 64] = a1.z; As[ak + 3][ar + 64] = a1.w;
        *(float4*)&Bs[bk][bc] = b0;
        *(float4*)&Bs[bk + 8][bc] = b1;
        __syncthreads();
#pragma unroll
        for (int k = 0; k < 16; k++) {
            float a[8], b[8];
            *(float4*)&a[0] = *(const float4*)&As[k][ty * 8];
            *(float4*)&a[4] = *(const float4*)&As[k][ty * 8 + 4];
            *(float4*)&b[0] = *(const float4*)&Bs[k][tx * 8];
            *(float4*)&b[4] = *(const float4*)&Bs[k][tx * 8 + 4];
#pragma unroll
            for (int i = 0; i < 8; i++)
#pragma unroll
                for (int j = 0; j < 8; j++) acc[i][j] = fmaf(a[i], b[j], acc[i][j]);
        }
    }
#pragma unroll
    for (int i = 0; i < 8; i++) {
        const int row = bm + ty * 8 + i;
#pragma unroll
        for (int j = 0; j < 8; j += 4) {
            const int col = bn + tx * 8 + j;
            const float4 bi = *(const float4*)&bias[col];
            float4 v = make_float4(softplus_fast(acc[i][j] + bi.x),
                                   softplus_fast(acc[i][j + 1] + bi.y),
                                   softplus_fast(acc[i][j + 2] + bi.z),
                                   softplus_fast(acc[i][j + 3] + bi.w));
            *(float4*)&C[(size_t)row * N + col] = v;
        }
    }
}

// ---------------- sum of 4 split-K partials -----------------
__global__ __launch_bounds__(256) void sum4(const float* __restrict__ p,
                                            float* __restrict__ out, int n) {
    const int i = (blockIdx.x * 256 + threadIdx.x) * 4;
    float4 a = *(const float4*)&p[i];
    float4 b = *(const float4*)&p[(size_t)n + i];
    float4 c = *(const float4*)&p[2 * (size_t)n + i];
    float4 d = *(const float4*)&p[3 * (size_t)n + i];
    *(float4*)&out[i] = make_float4((a.x + b.x) + (c.x + d.x),
                                    (a.y + b.y) + (c.y + d.y),
                                    (a.z + b.z) + (c.z + d.z),
                                    (a.w + b.w) + (c.w + d.w));
}

// ---------------- reduce 16 split-K partials [z][L][128] -> xdbl [L][96] ---------
__global__ __launch_bounds__(256) void g2reduce(const float* __restrict__ part,
                                                float* __restrict__ xdbl) {
    const int gid = blockIdx.x * 256 + threadIdx.x;
    if (gid < LL * NXDBL) {
        const int row = gid / NXDBL;
        const int col = gid - row * NXDBL;
        float s = 0.f;
#pragma unroll
        for (int z = 0; z < 16; z++) s += part[((size_t)z * LL + row) * 128 + col];
        xdbl[gid] = s;
    }
}

// ---------------- conv (k=4, causal) + silu -> xs (f32) + xs_b (bf16) ------------
__global__ __launch_bounds__(256) void conv_silu(const float* __restrict__ xc,
                                                 const float* __restrict__ cw,
                                                 const float* __restrict__ cb,
                                                 float* __restrict__ xs,
                                                 u16* __restrict__ xsb) {
    const int gid = blockIdx.x * 256 + threadIdx.x;  // l*DI + d
    const int l = gid >> 11;
    const int d = gid & (DI - 1);
    const float4 w = *(const float4*)&cw[d * 4];
    float acc = cb[d];
    const float wj[4] = {w.x, w.y, w.z, w.w};
#pragma unroll
    for (int j = 0; j < 4; j++) {
        const int li = l + j - 3;
        if (li >= 0) acc = fmaf(xc[(size_t)li * DI + d], wj[j], acc);
    }
    const float s = siluf_(acc);
    xs[gid] = s;
    xsb[gid] = f2b(s);
}

// ---------------- scan phase 1: per-chunk composition, 16 states/thread ---------
__global__ __launch_bounds__(256) void scan_phase1(const float* __restrict__ dt,
                                                   const float* __restrict__ xs,
                                                   const float* __restrict__ xdbl,
                                                   const float* __restrict__ A_log,
                                                   float* __restrict__ chA,
                                                   float* __restrict__ chB) {
    const int g = blockIdx.x * 256 + threadIdx.x;
    const int d = g & (DI - 1);
    const int c = g >> 11;
    float An2[NS], ap[NS], bc[NS];
    {
        float al[NS];
#pragma unroll
        for (int q = 0; q < 4; q++)
            *(float4*)&al[q * 4] = *(const float4*)&A_log[d * NS + q * 4];
#pragma unroll
        for (int n = 0; n < NS; n++) {
            An2[n] = -__expf(al[n]) * 1.44269504f;
            ap[n] = 1.f;
            bc[n] = 0.f;
        }
    }
    const int l0 = c * CHLEN;
    for (int l = l0; l < l0 + CHLEN; ++l) {
        const float dtv = dt[(size_t)l * DI + d];
        const float xsv = xs[(size_t)l * DI + d];
        const float dx = dtv * xsv;
        float bv[NS];
#pragma unroll
        for (int q = 0; q < 4; q++)
            *(float4*)&bv[q * 4] = *(const float4*)&xdbl[(size_t)l * NXDBL + DTR + q * 4];
#pragma unroll
        for (int n = 0; n < NS; n++) {
            const float al = __builtin_amdgcn_exp2f(dtv * An2[n]);
            ap[n] *= al;
            bc[n] = fmaf(al, bc[n], dx * bv[n]);
        }
    }
    const size_t o = ((size_t)c * DI + d) * NS;
#pragma unroll
    for (int q = 0; q < 4; q++) {
        *(float4*)&chA[o + q * 4] = *(float4*)&ap[q * 4];
        *(float4*)&chB[o + q * 4] = *(float4*)&bc[q * 4];
    }
}

// ---------------- scan phase 2: serial prefix over chunks (h0 in-place in chA) ---
__global__ __launch_bounds__(256) void scan_phase2(float* __restrict__ chA,
                                                   const float* __restrict__ chB,
                                                   float* __restrict__ hT_out) {
    const int t = blockIdx.x * 256 + threadIdx.x;  // 0..DI*NS-1
    float h = 0.f;
#pragma unroll 4
    for (int c = 0; c < NCHUNK; ++c) {
        const size_t o = (size_t)c * DI * NS + t;
        const float a = chA[o];
        const float b = chB[o];
        chA[o] = h;
        h = fmaf(a, h, b);
    }
    hT_out[t] = h;
}

// ---------------- scan phase 3: re-scan with h0, fused y epilogue (bf16 y) -------
__global__ __launch_bounds__(256) void scan_phase3(const float* __restrict__ dt,
                                                   const float* __restrict__ xs,
                                                   const float* __restrict__ xdbl,
                                                   const float* __restrict__ A_log,
                                                   const float* __restrict__ h0,
                                                   const float* __restrict__ Dw,
                                                   const float* __restrict__ res,
                                                   u16* __restrict__ yb) {
    const int g = blockIdx.x * 256 + threadIdx.x;
    const int d = g & (DI - 1);
    const int c = g >> 11;
    float An2[NS], h[NS];
    {
        float al[NS];
#pragma unroll
        for (int q = 0; q < 4; q++)
            *(float4*)&al[q * 4] = *(const float4*)&A_log[d * NS + q * 4];
#pragma unroll
        for (int n = 0; n < NS; n++) An2[n] = -__expf(al[n]) * 1.44269504f;
    }
    const size_t ho = ((size_t)c * DI + d) * NS;
#pragma unroll
    for (int q = 0; q < 4; q++) *(float4*)&h[q * 4] = *(const float4*)&h0[ho + q * 4];
    const float Dd = Dw[d];
    const int l0 = c * CHLEN;
    for (int l = l0; l < l0 + CHLEN; ++l) {
        const float dtv = dt[(size_t)l * DI + d];
        const float xsv = xs[(size_t)l * DI + d];
        const float resv = res[(size_t)l * DI + d];
        const float dx = dtv * xsv;
        float bv[NS], cv[NS];
#pragma unroll
        for (int q = 0; q < 4; q++) {
            *(float4*)&bv[q * 4] = *(const float4*)&xdbl[(size_t)l * NXDBL + DTR + q * 4];
            *(float4*)&cv[q * 4] =
                *(const float4*)&xdbl[(size_t)l * NXDBL + DTR + NS + q * 4];
        }
#pragma unroll
        for (int n = 0; n < NS; n++) {
            const float al = __builtin_amdgcn_exp2f(dtv * An2[n]);
            h[n] = fmaf(al, h[n], dx * bv[n]);
        }
        float y0 = 0.f, y1 = 0.f, y2 = 0.f, y3 = 0.f;
#pragma unroll
        for (int n = 0; n < NS; n += 4) {
            y0 = fmaf(h[n + 0], cv[n + 0], y0);
            y1 = fmaf(h[n + 1], cv[n + 1], y1);
            y2 = fmaf(h[n + 2], cv[n + 2], y2);
            y3 = fmaf(h[n + 3], cv[n + 3], y3);
        }
        float yv = ((y0 + y1) + (y2 + y3)) + xsv * Dd;
        yv *= siluf_(resv);
        yb[(size_t)l * DI + d] = f2b(yv);
    }
}

extern "C" void kernel_launch(void* const* d_in, const int* in_sizes, int n_in,
                              void* d_out, int out_size, void* d_ws, size_t ws_size,
                              hipStream_t stream) {
    const float* x = (const float*)d_in[0];
    const float* W_in = (const float*)d_in[1];
    const float* conv_w = (const float*)d_in[2];
    const float* conv_b = (const float*)d_in[3];
    const float* W_x = (const float*)d_in[4];
    const float* W_dt = (const float*)d_in[5];
    const float* b_dt = (const float*)d_in[6];
    const float* A_log = (const float*)d_in[7];
    const float* Dw = (const float*)d_in[8];
    const float* W_out = (const float*)d_in[9];
    float* out = (float*)d_out;

    // Flat workspace map (no aliasing), offsets in FLOATS. Total ~186 MB.
    float* ws = (float*)d_ws;
    float* xc       = ws;                     // L*DI f32      (4194304)
    float* res      = ws + 4194304;           // L*DI f32      (4194304)
    float* xs       = ws + 8388608;           // L*DI f32      (4194304)
    float* dt       = ws + 12582912;          // L*DI f32      (4194304)
    float* xdbl     = ws + 16777216;          // L*96 f32      (196608)
    float* chA      = ws + 16973824;          // NCHUNK*DI*NS  (4194304, ->h0)
    float* chB      = ws + 21168128;          // NCHUNK*DI*NS  (4194304)
    u16*   xb       = (u16*)(ws + 25362432);  // L*DM bf16     (1048576 f)
    u16*   W_inT_b  = (u16*)(ws + 26411008);  // 2DI*DM bf16   (2097152 f)
    u16*   W_outT_b = (u16*)(ws + 28508160);  // DM*DI bf16    (1048576 f)
    u16*   xs_b     = (u16*)(ws + 29556736);  // L*DI bf16     (2097152 f)
    u16*   W_xT_pad = (u16*)(ws + 31653888);  // 128*DI bf16   (131072 f)
    float* g2part   = ws + 31784960;          // 16*L*128 f32  (4194304 f)
    float* g4part   = ws + 35979264;          // 4*L*DM f32    (8388608 f)
    u16*   yb       = (u16*)(ws + 44367872);  // L*DI bf16     (2097152 f)

    // 1) fused prep: x->bf16, W_in^T, W_out^T, W_x^T(+pad) in ONE launch
    prep_all<<<PREP_BLOCKS, 256, 0, stream>>>(x, xb, W_in, W_inT_b, W_out, W_outT_b,
                                              W_x, W_xT_pad);
    // 2) x_and_res = x @ W_in  (bf16 MFMA) -> xc, res
    gemm_mfma<1, DM / 32><<<dim3(2 * DI / 128, LL / 128), 256, 0, stream>>>(
        xb, W_inT_b, xc, res, LL, 2 * DI, DM);
    // 3) conv + silu -> xs (f32) + xs_b (bf16)
    conv_silu<<<(LL * DI) / 256, 256, 0, stream>>>(xc, conv_w, conv_b, xs, xs_b);
    // 4) x_dbl = xs @ W_x  (bf16 MFMA, split-K=16 over z, N padded to 128)
    gemm_mfma<0, 4><<<dim3(1, LL / 128, 16), 256, 0, stream>>>(
        xs_b, W_xT_pad, g2part, nullptr, LL, 128, DI);
    g2reduce<<<(LL * NXDBL + 255) / 256, 256, 0, stream>>>(g2part, xdbl);
    // 5) dt = softplus(dt_r @ W_dt + b_dt)  (fp32 128^2 8x8)
    gemm128_dt<<<dim3(DI / 128, LL / 128), 256, 0, stream>>>(xdbl, W_dt, b_dt, dt,
                                                             DI, DTR, NXDBL);
    // 6) chunked scan (NCHUNK=128 -> 1024 blocks for phase1/3)
    scan_phase1<<<(DI * NCHUNK) / 256, 256, 0, stream>>>(dt, xs, xdbl, A_log, chA, chB);
    scan_phase2<<<(DI * NS) / 256, 256, 0, stream>>>(chA, chB, out + (size_t)LL * DM);
    scan_phase3<<<(DI * NCHUNK) / 256, 256, 0, stream>>>(dt, xs, xdbl, A_log, chA, Dw,
                                                         res, yb);
    // 7) out = y @ W_out (bf16 MFMA, split-K=4 over z -> 512 blocks, 2/CU)
    gemm_mfma<0, DI / 128><<<dim3(DM / 128, LL / 128, 4), 256, 0, stream>>>(
        yb, W_outT_b, g4part, nullptr, LL, DM, DI);
    sum4<<<(LL * DM) / 1024, 256, 0, stream>>>(g4part, out, LL * DM);
}

// Round 12
// 165.017 us; speedup vs baseline: 1.2489x; 1.0407x over previous
//
#include <hip/hip_runtime.h>
#include <math.h>

#define DM 1024
#define DI 2048
#define NS 16
#define DTR 64
#define LL 2048
#define NXDBL 96      // DTR + 2*NS
#define NCHUNK 128
#define CHLEN 16      // LL / NCHUNK

typedef unsigned short u16;
typedef __attribute__((ext_vector_type(8))) short short8;
typedef __attribute__((ext_vector_type(4))) float f32x4;

__device__ __forceinline__ float sigmoidf_(float x) { return 1.f / (1.f + __expf(-x)); }
__device__ __forceinline__ float siluf_(float x) { return x * sigmoidf_(x); }
__device__ __forceinline__ float softplus_fast(float x) {
    return fmaxf(x, 0.f) + __logf(1.f + __expf(-fabsf(x)));
}
__device__ __forceinline__ u16 f2b(float f) {  // fp32 -> bf16 RNE
    unsigned u = __float_as_uint(f);
    return (u16)((u + 0x7FFFu + ((u >> 16) & 1u)) >> 16);
}
__device__ __forceinline__ float b2f(u16 h) {
    return __uint_as_float(((unsigned)h) << 16);
}

// ---------------- fused prep: x->bf16, W_in^T, W_out^T, W_x^T + zero-pad --------
__device__ __forceinline__ void convT_dev(const float* __restrict__ src,
                                          u16* __restrict__ dst, int R, int C,
                                          int bflat, int gridx, float (*t)[33]) {
    const int tx = threadIdx.x & 31, ty = threadIdx.x >> 5;  // ty 0..7
    const int c0 = (bflat % gridx) * 32, r0 = (bflat / gridx) * 32;
#pragma unroll
    for (int i = 0; i < 4; i++)
        t[ty + i * 8][tx] = src[(size_t)(r0 + ty + i * 8) * C + c0 + tx];
    __syncthreads();
#pragma unroll
    for (int i = 0; i < 4; i++)
        dst[(size_t)(c0 + ty + i * 8) * R + r0 + tx] = f2b(t[tx][ty + i * 8]);
}

// block ranges: [0,2048) x-convert | [2048,6144) W_in^T | [6144,8192) W_out^T |
//               [8192,8384) W_x^T | [8384,8640) zero-pad rows 96..127
#define PREP_BLOCKS 8640
__global__ __launch_bounds__(256) void prep_all(const float* __restrict__ x,
                                                u16* __restrict__ xb,
                                                const float* __restrict__ W_in,
                                                u16* __restrict__ W_inT,
                                                const float* __restrict__ W_out,
                                                u16* __restrict__ W_outT,
                                                const float* __restrict__ W_x,
                                                u16* __restrict__ W_xT_pad) {
    __shared__ float t[32][33];
    const int b = blockIdx.x;
    if (b < 2048) {
        const int i = (b * 256 + threadIdx.x) * 4;
        float4 v = *(const float4*)&x[i];
        u16 o[4] = {f2b(v.x), f2b(v.y), f2b(v.z), f2b(v.w)};
        *(ushort4*)&xb[i] = *(ushort4*)o;
    } else if (b < 6144) {
        convT_dev(W_in, W_inT, DM, 2 * DI, b - 2048, 2 * DI / 32, t);
    } else if (b < 8192) {
        convT_dev(W_out, W_outT, DI, DM, b - 6144, DM / 32, t);
    } else if (b < 8384) {
        convT_dev(W_x, W_xT_pad, DI, NXDBL, b - 8192, NXDBL / 32, t);
    } else {
        const int i = (b - 8384) * 256 + threadIdx.x;
        if (i < 32 * DI) W_xT_pad[96 * DI + i] = 0;
    }
}

// ---------------- bf16 MFMA GEMM: C[M][N] = A[M][K] @ Bt[N][K]^T -----------------
// 128x128 tile, BK=32, K = NSTEPS*32. 3-buffer LDS pipeline, prefetch distance 2,
// counted s_waitcnt vmcnt(N) + raw s_barrier. LDS k-group XOR swizzle on the
// per-lane GLOBAL source (write) and the ds_read offset (read); LDS stays linear.
// XCD-aware block swizzle: flat id -> (h&7)*(nb/8)+(h>>3), column-major decompose
// so each XCD owns a contiguous bx range (B panels L2-resident). nb%8==0 always.
// EPI==1: cols [0,DI) -> C0 as bf16 (u16); cols [DI,2DI) -> C1 f32 (res), ld=DI.
// EPI==0: fp32 partial to (float*)C0 + z*M*nreal, ld=nreal, store iff col<nreal.
#define WAITV(N) asm volatile("s_waitcnt vmcnt(" #N ")" ::: "memory")
template <int EPI, int NSTEPS>
__global__ __launch_bounds__(256) void gemm_mfma(const u16* __restrict__ A,
                                                 const u16* __restrict__ Bt,
                                                 void* __restrict__ C0,
                                                 void* __restrict__ C1,
                                                 int M, int N, int lda, int nreal) {
    __shared__ u16 As[3][128 * 32];
    __shared__ u16 Bs[3][128 * 32];
    const int tid = threadIdx.x;
    const int lane = tid & 63;
    const int wave = tid >> 6;
    // XCD-aware swizzle (bijective; nb multiple of 8)
    const int gx = gridDim.x, gy = gridDim.y;
    const int nb = gx * gy;
    const int h = blockIdx.y * gx + blockIdx.x;
    const int f = (h & 7) * (nb >> 3) + (h >> 3);
    const int bm = (f % gy) * 128, bn = (f / gy) * 128;
    const int wr = wave >> 1, wc = wave & 1;
    const int k_off = blockIdx.z * (NSTEPS * 32);

    f32x4 acc[4][4];
#pragma unroll
    for (int m = 0; m < 4; m++)
#pragma unroll
        for (int n = 0; n < 4; n++) acc[m][n] = (f32x4)0.f;

    // staging: thread tid -> (row = tid>>2, kg = tid&3), LDS linear at tid*16B.
    const int srow = tid >> 2;
    const int swz = (tid >> 3) & 3;                    // (srow>>1)&3
    const int skel = (((tid & 3) ^ swz) << 3);         // swizzled k elem offset
    const u16* Ag0 = A + (size_t)(bm + srow) * lda + k_off + skel;
    const u16* Ag1 = A + (size_t)(bm + 64 + srow) * lda + k_off + skel;
    const u16* Bg0 = Bt + (size_t)(bn + srow) * lda + k_off + skel;
    const u16* Bg1 = Bt + (size_t)(bn + 64 + srow) * lda + k_off + skel;
    u16* Asl = &As[0][0] + tid * 8;
    u16* Bsl = &Bs[0][0] + tid * 8;

    // fragment read offsets (u16 units), same swizzle on the kg index
    const int rsw = (lane >> 1) & 3;                   // row bits 1-2
    const int arow = (wr * 64 + (lane & 15)) * 32 + (((lane >> 4) ^ rsw) << 3);
    const int brow = (wc * 64 + (lane & 15)) * 32 + (((lane >> 4) ^ rsw) << 3);

#define STAGE(buf, ks)                                                               \
    do {                                                                             \
        __builtin_amdgcn_global_load_lds(                                            \
            (const __attribute__((address_space(1))) unsigned*)(Ag0 + (ks)),         \
            (__attribute__((address_space(3))) unsigned*)(Asl + (buf) * 4096),       \
            16, 0, 0);                                                               \
        __builtin_amdgcn_global_load_lds(                                            \
            (const __attribute__((address_space(1))) unsigned*)(Ag1 + (ks)),         \
            (__attribute__((address_space(3))) unsigned*)(Asl + (buf) * 4096 + 2048),\
            16, 0, 0);                                                               \
        __builtin_amdgcn_global_load_lds(                                            \
            (const __attribute__((address_space(1))) unsigned*)(Bg0 + (ks)),         \
            (__attribute__((address_space(3))) unsigned*)(Bsl + (buf) * 4096),       \
            16, 0, 0);                                                               \
        __builtin_amdgcn_global_load_lds(                                            \
            (const __attribute__((address_space(1))) unsigned*)(Bg1 + (ks)),         \
            (__attribute__((address_space(3))) unsigned*)(Bsl + (buf) * 4096 + 2048),\
            16, 0, 0);                                                               \
    } while (0)

#define COMPUTE(buf)                                                                 \
    do {                                                                             \
        short8 av[4], bv[4];                                                         \
        _Pragma("unroll") for (int m = 0; m < 4; m++)                                \
            av[m] = *(const short8*)&As[buf][arow + m * 512];                        \
        _Pragma("unroll") for (int n = 0; n < 4; n++)                                \
            bv[n] = *(const short8*)&Bs[buf][brow + n * 512];                        \
        _Pragma("unroll") for (int m = 0; m < 4; m++)                                \
            _Pragma("unroll") for (int n = 0; n < 4; n++)                            \
                acc[m][n] = __builtin_amdgcn_mfma_f32_16x16x32_bf16(av[m], bv[n],    \
                                                                    acc[m][n], 0, 0, 0); \
    } while (0)

    STAGE(0, 0);
    if (NSTEPS > 1) STAGE(1, 32);
#pragma unroll
    for (int s = 0; s < NSTEPS; ++s) {
        if (s + 2 < NSTEPS) {
            STAGE((s + 2) % 3, (s + 2) * 32);
            WAITV(8);                      // oldest 4 (tile s) complete; 8 in flight
        } else if (s + 1 < NSTEPS) {
            WAITV(4);
        } else {
            WAITV(0);
        }
        __builtin_amdgcn_s_barrier();      // tile s visible to all waves
        COMPUTE(s % 3);
        __builtin_amdgcn_s_barrier();      // reads done before buf reuse
    }
#undef STAGE
#undef COMPUTE

    const int crow0 = bm + wr * 64 + (lane >> 4) * 4;
    const int ccol0 = bn + wc * 64 + (lane & 15);
#pragma unroll
    for (int m = 0; m < 4; m++)
#pragma unroll
        for (int n = 0; n < 4; n++) {
            const int col = ccol0 + n * 16;
#pragma unroll
            for (int r = 0; r < 4; r++) {
                const int row = crow0 + m * 16 + r;
                const float v = acc[m][n][r];
                if (EPI == 1) {
                    if (col < DI)
                        ((u16*)C0)[(size_t)row * DI + col] = f2b(v);
                    else
                        ((float*)C1)[(size_t)row * DI + col - DI] = v;
                } else {
                    float* C0z = (float*)C0 + (size_t)blockIdx.z * M * nreal;
                    if (col < nreal) C0z[(size_t)row * nreal + col] = v;
                }
            }
        }
}

// ---------------- fp32 GEMM 128x128 tile, 8x8 micro, BK=16: dt path (K=64) -------
__global__ __launch_bounds__(256) void gemm128_dt(const float* __restrict__ A,
                                                  const float* __restrict__ B,
                                                  const float* __restrict__ bias,
                                                  float* __restrict__ C,
                                                  int N, int K, int lda) {
    __shared__ float As[16][128];
    __shared__ float Bs[16][128];
    const int tid = threadIdx.x;
    const int bm = blockIdx.y * 128, bn = blockIdx.x * 128;
    const int ty = tid >> 4, tx = tid & 15;
    float acc[8][8];
#pragma unroll
    for (int i = 0; i < 8; i++)
#pragma unroll
        for (int j = 0; j < 8; j++) acc[i][j] = 0.f;

    const int ar = tid >> 2, ak = (tid & 3) << 2;
    const int bk = tid >> 5, bc = (tid & 31) << 2;

    for (int k0 = 0; k0 < K; k0 += 16) {
        float4 a0 = *(const float4*)&A[(size_t)(bm + ar) * lda + k0 + ak];
        float4 a1 = *(const float4*)&A[(size_t)(bm + ar + 64) * lda + k0 + ak];
        float4 b0 = *(const float4*)&B[(size_t)(k0 + bk) * N + bn + bc];
        float4 b1 = *(const float4*)&B[(size_t)(k0 + bk + 8) * N + bn + bc];
        __syncthreads();
        As[ak + 0][ar] = a0.x; As[ak + 1][ar] = a0.y;
        As[ak + 2][ar] = a0.z; As[ak + 3][ar] = a0.w;
        As[ak + 0][ar + 64] = a1.x; As[ak + 1][ar + 64] = a1.y;
        As[ak + 2][ar + 64] = a1.z; As[ak + 3][ar + 64] = a1.w;
        *(float4*)&Bs[bk][bc] = b0;
        *(float4*)&Bs[bk + 8][bc] = b1;
        __syncthreads();
#pragma unroll
        for (int k = 0; k < 16; k++) {
            float a[8], b[8];
            *(float4*)&a[0] = *(const float4*)&As[k][ty * 8];
            *(float4*)&a[4] = *(const float4*)&As[k][ty * 8 + 4];
            *(float4*)&b[0] = *(const float4*)&Bs[k][tx * 8];
            *(float4*)&b[4] = *(const float4*)&Bs[k][tx * 8 + 4];
#pragma unroll
            for (int i = 0; i < 8; i++)
#pragma unroll
                for (int j = 0; j < 8; j++) acc[i][j] = fmaf(a[i], b[j], acc[i][j]);
        }
    }
#pragma unroll
    for (int i = 0; i < 8; i++) {
        const int row = bm + ty * 8 + i;
#pragma unroll
        for (int j = 0; j < 8; j += 4) {
            const int col = bn + tx * 8 + j;
            const float4 bi = *(const float4*)&bias[col];
            float4 v = make_float4(softplus_fast(acc[i][j] + bi.x),
                                   softplus_fast(acc[i][j + 1] + bi.y),
                                   softplus_fast(acc[i][j + 2] + bi.z),
                                   softplus_fast(acc[i][j + 3] + bi.w));
            *(float4*)&C[(size_t)row * N + col] = v;
        }
    }
}

// ---------------- sum of 4 split-K partials -----------------
__global__ __launch_bounds__(256) void sum4(const float* __restrict__ p,
                                            float* __restrict__ out, int n) {
    const int i = (blockIdx.x * 256 + threadIdx.x) * 4;
    float4 a = *(const float4*)&p[i];
    float4 b = *(const float4*)&p[(size_t)n + i];
    float4 c = *(const float4*)&p[2 * (size_t)n + i];
    float4 d = *(const float4*)&p[3 * (size_t)n + i];
    *(float4*)&out[i] = make_float4((a.x + b.x) + (c.x + d.x),
                                    (a.y + b.y) + (c.y + d.y),
                                    (a.z + b.z) + (c.z + d.z),
                                    (a.w + b.w) + (c.w + d.w));
}

// ---------------- reduce 16 split-K partials [z][L][96] -> xdbl [L][96] ----------
__global__ __launch_bounds__(256) void g2reduce(const float* __restrict__ part,
                                                float* __restrict__ xdbl) {
    const int gid = blockIdx.x * 256 + threadIdx.x;
    if (gid < LL * NXDBL) {
        float s = 0.f;
#pragma unroll
        for (int z = 0; z < 16; z++) s += part[(size_t)z * LL * NXDBL + gid];
        xdbl[gid] = s;
    }
}

// ---------------- conv (k=4, causal) + silu: bf16 xc -> xs (f32) + xs_b (bf16) ---
__global__ __launch_bounds__(256) void conv_silu(const u16* __restrict__ xcb,
                                                 const float* __restrict__ cw,
                                                 const float* __restrict__ cb,
                                                 float* __restrict__ xs,
                                                 u16* __restrict__ xsb) {
    const int gid = blockIdx.x * 256 + threadIdx.x;  // l*DI + d
    const int l = gid >> 11;
    const int d = gid & (DI - 1);
    const float4 w = *(const float4*)&cw[d * 4];
    float acc = cb[d];
    const float wj[4] = {w.x, w.y, w.z, w.w};
#pragma unroll
    for (int j = 0; j < 4; j++) {
        const int li = l + j - 3;
        if (li >= 0) acc = fmaf(b2f(xcb[(size_t)li * DI + d]), wj[j], acc);
    }
    const float s = siluf_(acc);
    xs[gid] = s;
    xsb[gid] = f2b(s);
}

// ---------------- scan phase 1: per-chunk composition, 16 states/thread ---------
__global__ __launch_bounds__(256) void scan_phase1(const float* __restrict__ dt,
                                                   const float* __restrict__ xs,
                                                   const float* __restrict__ xdbl,
                                                   const float* __restrict__ A_log,
                                                   float* __restrict__ chA,
                                                   float* __restrict__ chB) {
    const int g = blockIdx.x * 256 + threadIdx.x;
    const int d = g & (DI - 1);
    const int c = g >> 11;
    float An2[NS], ap[NS], bc[NS];
    {
        float al[NS];
#pragma unroll
        for (int q = 0; q < 4; q++)
            *(float4*)&al[q * 4] = *(const float4*)&A_log[d * NS + q * 4];
#pragma unroll
        for (int n = 0; n < NS; n++) {
            An2[n] = -__expf(al[n]) * 1.44269504f;
            ap[n] = 1.f;
            bc[n] = 0.f;
        }
    }
    const int l0 = c * CHLEN;
    for (int l = l0; l < l0 + CHLEN; ++l) {
        const float dtv = dt[(size_t)l * DI + d];
        const float xsv = xs[(size_t)l * DI + d];
        const float dx = dtv * xsv;
        float bv[NS];
#pragma unroll
        for (int q = 0; q < 4; q++)
            *(float4*)&bv[q * 4] = *(const float4*)&xdbl[(size_t)l * NXDBL + DTR + q * 4];
#pragma unroll
        for (int n = 0; n < NS; n++) {
            const float al = __builtin_amdgcn_exp2f(dtv * An2[n]);
            ap[n] *= al;
            bc[n] = fmaf(al, bc[n], dx * bv[n]);
        }
    }
    const size_t o = ((size_t)c * DI + d) * NS;
#pragma unroll
    for (int q = 0; q < 4; q++) {
        *(float4*)&chA[o + q * 4] = *(float4*)&ap[q * 4];
        *(float4*)&chB[o + q * 4] = *(float4*)&bc[q * 4];
    }
}

// ---------------- scan phase 2: serial prefix over chunks (h0 in-place in chA) ---
__global__ __launch_bounds__(256) void scan_phase2(float* __restrict__ chA,
                                                   const float* __restrict__ chB,
                                                   float* __restrict__ hT_out) {
    const int t = blockIdx.x * 256 + threadIdx.x;  // 0..DI*NS-1
    float h = 0.f;
#pragma unroll 16
    for (int c = 0; c < NCHUNK; ++c) {
        const size_t o = (size_t)c * DI * NS + t;
        const float a = chA[o];
        const float b = chB[o];
        chA[o] = h;
        h = fmaf(a, h, b);
    }
    hT_out[t] = h;
}

// ---------------- scan phase 3: re-scan with h0, fused y epilogue (bf16 y) -------
__global__ __launch_bounds__(256) void scan_phase3(const float* __restrict__ dt,
                                                   const float* __restrict__ xs,
                                                   const float* __restrict__ xdbl,
                                                   const float* __restrict__ A_log,
                                                   const float* __restrict__ h0,
                                                   const float* __restrict__ Dw,
                                                   const float* __restrict__ res,
                                                   u16* __restrict__ yb) {
    const int g = blockIdx.x * 256 + threadIdx.x;
    const int d = g & (DI - 1);
    const int c = g >> 11;
    float An2[NS], h[NS];
    {
        float al[NS];
#pragma unroll
        for (int q = 0; q < 4; q++)
            *(float4*)&al[q * 4] = *(const float4*)&A_log[d * NS + q * 4];
#pragma unroll
        for (int n = 0; n < NS; n++) An2[n] = -__expf(al[n]) * 1.44269504f;
    }
    const size_t ho = ((size_t)c * DI + d) * NS;
#pragma unroll
    for (int q = 0; q < 4; q++) *(float4*)&h[q * 4] = *(const float4*)&h0[ho + q * 4];
    const float Dd = Dw[d];
    const int l0 = c * CHLEN;
    for (int l = l0; l < l0 + CHLEN; ++l) {
        const float dtv = dt[(size_t)l * DI + d];
        const float xsv = xs[(size_t)l * DI + d];
        const float resv = res[(size_t)l * DI + d];
        const float dx = dtv * xsv;
        float bv[NS], cv[NS];
#pragma unroll
        for (int q = 0; q < 4; q++) {
            *(float4*)&bv[q * 4] = *(const float4*)&xdbl[(size_t)l * NXDBL + DTR + q * 4];
            *(float4*)&cv[q * 4] =
                *(const float4*)&xdbl[(size_t)l * NXDBL + DTR + NS + q * 4];
        }
#pragma unroll
        for (int n = 0; n < NS; n++) {
            const float al = __builtin_amdgcn_exp2f(dtv * An2[n]);
            h[n] = fmaf(al, h[n], dx * bv[n]);
        }
        float y0 = 0.f, y1 = 0.f, y2 = 0.f, y3 = 0.f;
#pragma unroll
        for (int n = 0; n < NS; n += 4) {
            y0 = fmaf(h[n + 0], cv[n + 0], y0);
            y1 = fmaf(h[n + 1], cv[n + 1], y1);
            y2 = fmaf(h[n + 2], cv[n + 2], y2);
            y3 = fmaf(h[n + 3], cv[n + 3], y3);
        }
        float yv = ((y0 + y1) + (y2 + y3)) + xsv * Dd;
        yv *= siluf_(resv);
        yb[(size_t)l * DI + d] = f2b(yv);
    }
}

extern "C" void kernel_launch(void* const* d_in, const int* in_sizes, int n_in,
                              void* d_out, int out_size, void* d_ws, size_t ws_size,
                              hipStream_t stream) {
    const float* x = (const float*)d_in[0];
    const float* W_in = (const float*)d_in[1];
    const float* conv_w = (const float*)d_in[2];
    const float* conv_b = (const float*)d_in[3];
    const float* W_x = (const float*)d_in[4];
    const float* W_dt = (const float*)d_in[5];
    const float* b_dt = (const float*)d_in[6];
    const float* A_log = (const float*)d_in[7];
    const float* Dw = (const float*)d_in[8];
    const float* W_out = (const float*)d_in[9];
    float* out = (float*)d_out;

    // Flat workspace map (no aliasing), offsets in FLOATS. Total ~186 MB.
    float* ws = (float*)d_ws;
    u16*   xcb      = (u16*)ws;               // L*DI bf16     (slot 4194304 f)
    float* res      = ws + 4194304;           // L*DI f32      (4194304)
    float* xs       = ws + 8388608;           // L*DI f32      (4194304)
    float* dt       = ws + 12582912;          // L*DI f32      (4194304)
    float* xdbl     = ws + 16777216;          // L*96 f32      (196608)
    float* chA      = ws + 16973824;          // NCHUNK*DI*NS  (4194304, ->h0)
    float* chB      = ws + 21168128;          // NCHUNK*DI*NS  (4194304)
    u16*   xb       = (u16*)(ws + 25362432);  // L*DM bf16     (1048576 f)
    u16*   W_inT_b  = (u16*)(ws + 26411008);  // 2DI*DM bf16   (2097152 f)
    u16*   W_outT_b = (u16*)(ws + 28508160);  // DM*DI bf16    (1048576 f)
    u16*   xs_b     = (u16*)(ws + 29556736);  // L*DI bf16     (2097152 f)
    u16*   W_xT_pad = (u16*)(ws + 31653888);  // 128*DI bf16   (131072 f)
    float* g2part   = ws + 31784960;          // 16*L*96 f32   (3145728 f, slot 4194304)
    float* g4part   = ws + 35979264;          // 4*L*DM f32    (8388608 f)
    u16*   yb       = (u16*)(ws + 44367872);  // L*DI bf16     (2097152 f)

    // 1) fused prep: x->bf16, W_in^T, W_out^T, W_x^T(+pad) in ONE launch
    prep_all<<<PREP_BLOCKS, 256, 0, stream>>>(x, xb, W_in, W_inT_b, W_out, W_outT_b,
                                              W_x, W_xT_pad);
    // 2) x_and_res = x @ W_in  (bf16 MFMA) -> xcb (bf16), res (f32)
    gemm_mfma<1, DM / 32><<<dim3(2 * DI / 128, LL / 128), 256, 0, stream>>>(
        xb, W_inT_b, xcb, res, LL, 2 * DI, DM, 2 * DI);
    // 3) conv + silu -> xs (f32) + xs_b (bf16)
    conv_silu<<<(LL * DI) / 256, 256, 0, stream>>>(xcb, conv_w, conv_b, xs, xs_b);
    // 4) x_dbl = xs @ W_x  (bf16 MFMA, split-K=16 over z, N padded to 128,
    //    partials stored at true ld=96)
    gemm_mfma<0, 4><<<dim3(1, LL / 128, 16), 256, 0, stream>>>(
        xs_b, W_xT_pad, g2part, nullptr, LL, 128, DI, NXDBL);
    g2reduce<<<(LL * NXDBL + 255) / 256, 256, 0, stream>>>(g2part, xdbl);
    // 5) dt = softplus(dt_r @ W_dt + b_dt)  (fp32 128^2 8x8)
    gemm128_dt<<<dim3(DI / 128, LL / 128), 256, 0, stream>>>(xdbl, W_dt, b_dt, dt,
                                                             DI, DTR, NXDBL);
    // 6) chunked scan (NCHUNK=128 -> 1024 blocks for phase1/3)
    scan_phase1<<<(DI * NCHUNK) / 256, 256, 0, stream>>>(dt, xs, xdbl, A_log, chA, chB);
    scan_phase2<<<(DI * NS) / 256, 256, 0, stream>>>(chA, chB, out + (size_t)LL * DM);
    scan_phase3<<<(DI * NCHUNK) / 256, 256, 0, stream>>>(dt, xs, xdbl, A_log, chA, Dw,
                                                         res, yb);
    // 7) out = y @ W_out (bf16 MFMA, split-K=4 over z -> 512 blocks, 2/CU)
    gemm_mfma<0, DI / 128><<<dim3(DM / 128, LL / 128, 4), 256, 0, stream>>>(
        yb, W_outT_b, g4part, nullptr, LL, DM, DI, DM);
    sum4<<<(LL * DM) / 1024, 256, 0, stream>>>(g4part, out, LL * DM);
}